// Round 1
// baseline (1303.695 us; speedup 1.0000x reference)
//
#include <hip/hip_runtime.h>
#include <math.h>

#define N_NODES 50000
#define N_EDGES 800000
#define N_TOT   850000   // E + N self-loops
#define EPS_BN  1e-5f
#define GAT_SLOPE 0.2f
#define ACT_SLOPE 0.01f

// ---- monotone float<->uint encoding for atomicMax on floats ----
__device__ __forceinline__ unsigned enc_f32(float f) {
    unsigned b = __float_as_uint(f);
    return (b & 0x80000000u) ? ~b : (b | 0x80000000u);
}
__device__ __forceinline__ float dec_f32(unsigned u) {
    unsigned b = (u & 0x80000000u) ? (u ^ 0x80000000u) : ~u;
    return __uint_as_float(b);
}

// ---- GEMM: out[n x C] = x[n x K] @ W[K x C] (+bias). blockDim == C. ----
// ROWS rows per block staged in LDS; safe for in-place (reads staged before writes).
template<int K, int C, int ROWS>
__global__ void gemm_rows(const float* __restrict__ x, const float* __restrict__ W,
                          const float* __restrict__ bias, float* __restrict__ out, int n) {
    __shared__ float xs[ROWS * K];
    const int row0 = blockIdx.x * ROWS;
    const int t = threadIdx.x;
    for (int i = t; i < ROWS * K; i += C) {
        int r = i / K;
        xs[i] = (row0 + r < n) ? x[(size_t)row0 * K + i] : 0.f;
    }
    __syncthreads();
    float acc[ROWS];
#pragma unroll
    for (int r = 0; r < ROWS; ++r) acc[r] = 0.f;
    for (int k = 0; k < K; ++k) {
        float w = W[(size_t)k * C + t];
#pragma unroll
        for (int r = 0; r < ROWS; ++r) acc[r] += xs[r * K + k] * w;
    }
    float b = bias ? bias[t] : 0.f;
#pragma unroll
    for (int r = 0; r < ROWS; ++r)
        if (row0 + r < n) out[(size_t)(row0 + r) * C + t] = acc[r] + b;
}

// ---- per-node attention dots: e[n]=h[n]·a_s, f[n]=h[n]·a_d. one wave/node ----
template<int C>
__global__ void node_dots(const float* __restrict__ h, const float* __restrict__ a_s,
                          const float* __restrict__ a_d, float* __restrict__ e_n,
                          float* __restrict__ f_n) {
    int node = (int)((blockIdx.x * (size_t)blockDim.x + threadIdx.x) >> 6);
    int lane = threadIdx.x & 63;
    if (node >= N_NODES) return;
    float es = 0.f, fs = 0.f;
    for (int c = lane; c < C; c += 64) {
        float v = h[(size_t)node * C + c];
        es += v * a_s[c];
        fs += v * a_d[c];
    }
    for (int off = 32; off > 0; off >>= 1) {
        es += __shfl_down(es, off, 64);
        fs += __shfl_down(fs, off, 64);
    }
    if (lane == 0) { e_n[node] = es; f_n[node] = fs; }
}

// ---- CSR build over dst ----
__global__ void csr_count(const int* __restrict__ ei, int* __restrict__ cnt) {
    int e = blockIdx.x * blockDim.x + threadIdx.x;
    if (e >= N_TOT) return;
    int d = (e < N_EDGES) ? ei[N_EDGES + e] : (e - N_EDGES);
    atomicAdd(&cnt[d], 1);
}

__global__ void exclusive_scan(const int* __restrict__ cnt, int* __restrict__ ptr) {
    __shared__ int sh[1024];
    __shared__ int s_running;
    int t = threadIdx.x;
    if (t == 0) s_running = 0;
    __syncthreads();
    for (int base = 0; base < N_NODES; base += 1024) {
        int v = (base + t < N_NODES) ? cnt[base + t] : 0;
        sh[t] = v;
        __syncthreads();
        for (int off = 1; off < 1024; off <<= 1) {
            int add = (t >= off) ? sh[t - off] : 0;
            __syncthreads();
            sh[t] += add;
            __syncthreads();
        }
        int incl = sh[t];
        if (base + t < N_NODES) ptr[base + t] = s_running + incl - v;
        __syncthreads();
        if (t == 1023) s_running += incl;
        __syncthreads();
    }
    if (t == 0) ptr[N_NODES] = s_running;
}

__global__ void csr_fill(const int* __restrict__ ei, const int* __restrict__ ptr,
                         int* __restrict__ cur, int* __restrict__ idx) {
    int e = blockIdx.x * blockDim.x + threadIdx.x;
    if (e >= N_TOT) return;
    int d = (e < N_EDGES) ? ei[N_EDGES + e] : (e - N_EDGES);
    int pos = ptr[d] + atomicAdd(&cur[d], 1);
    idx[pos] = e;
}

// ---- edge logits + segment max over dst ----
__global__ void edge_logits_max(const int* __restrict__ ei, const float* __restrict__ e_n,
                                const float* __restrict__ f_n, float* __restrict__ logits,
                                unsigned* __restrict__ mx) {
    int e = blockIdx.x * blockDim.x + threadIdx.x;
    if (e >= N_TOT) return;
    int s, d;
    if (e < N_EDGES) { s = ei[e]; d = ei[N_EDGES + e]; }
    else { s = e - N_EDGES; d = s; }
    float lg = e_n[s] + f_n[d];
    lg = lg > 0.f ? lg : GAT_SLOPE * lg;
    logits[e] = lg;
    atomicMax(&mx[d], enc_f32(lg));
}

// ---- softmax-weighted gather aggregation: block per dst node, blockDim == C ----
template<int C>
__global__ void aggregate(const float* __restrict__ h, const int* __restrict__ ei,
                          const int* __restrict__ ptr, const int* __restrict__ idx,
                          const float* __restrict__ logits, const unsigned* __restrict__ mx,
                          const float* __restrict__ bias, float* __restrict__ out) {
    int d = blockIdx.x;
    int t = threadIdx.x;
    float m = dec_f32(mx[d]);
    int b0 = ptr[d], b1 = ptr[d + 1];
    float acc = 0.f, den = 0.f;
    for (int j = b0; j < b1; ++j) {
        int g = idx[j];
        int s = (g < N_EDGES) ? ei[g] : (g - N_EDGES);
        float ex = __expf(logits[g] - m);
        acc += ex * h[(size_t)s * C + t];
        den += ex;   // identical across threads (self-loop guarantees den>0)
    }
    out[(size_t)d * C + t] = acc / den + bias[t];
}

// ---- BatchNorm stats: column partial sums (blockDim == C), f64 atomics ----
template<int C>
__global__ void bn_stats(const float* __restrict__ x, double* __restrict__ sum,
                         double* __restrict__ sumsq) {
    int t = threadIdx.x;
    double s = 0., q = 0.;
    for (int r = blockIdx.x; r < N_NODES; r += gridDim.x) {
        float v = x[(size_t)r * C + t];
        s += v;
        q += (double)v * v;
    }
    atomicAdd(&sum[t], s);
    atomicAdd(&sumsq[t], q);
}

template<int C>
__global__ void bn_apply(float* __restrict__ x, const double* __restrict__ sum,
                         const double* __restrict__ sumsq, const float* __restrict__ gamma,
                         const float* __restrict__ beta) {
    size_t i = (size_t)blockIdx.x * blockDim.x + threadIdx.x;
    if (i >= (size_t)N_NODES * C) return;
    int c = (int)(i % C);
    float mu = (float)(sum[c] / N_NODES);
    float var = (float)(sumsq[c] / N_NODES) - mu * mu;
    float v = x[i];
    float y = (v - mu) * rsqrtf(var + EPS_BN) * gamma[c] + beta[c];
    y = y > 0.f ? y : ACT_SLOPE * y;
    x[i] = y;
}

extern "C" void kernel_launch(void* const* d_in, const int* in_sizes, int n_in,
                              void* d_out, int out_size, void* d_ws, size_t ws_size,
                              hipStream_t stream) {
    const float* emb  = (const float*)d_in[0];
    const int*   ei   = (const int*)  d_in[1];
    const float* W1   = (const float*)d_in[2];
    const float* as1  = (const float*)d_in[3];
    const float* ad1  = (const float*)d_in[4];
    const float* b1   = (const float*)d_in[5];
    const float* g1   = (const float*)d_in[6];
    const float* be1  = (const float*)d_in[7];
    const float* W2   = (const float*)d_in[8];
    const float* as2  = (const float*)d_in[9];
    const float* ad2  = (const float*)d_in[10];
    const float* b2   = (const float*)d_in[11];
    const float* g2   = (const float*)d_in[12];
    const float* be2  = (const float*)d_in[13];
    const float* Wf   = (const float*)d_in[14];
    const float* bf   = (const float*)d_in[15];
    float* out = (float*)d_out;

    char* w = (char*)d_ws;
    auto alloc = [&](size_t bytes) {
        char* p = w;
        w += (bytes + 255) & ~(size_t)255;
        return (void*)p;
    };
    float*    bufA   = (float*)   alloc((size_t)N_NODES * 256 * 4); // h1 then h2
    float*    x1     = (float*)   alloc((size_t)N_NODES * 128 * 4);
    float*    e_n    = (float*)   alloc((size_t)N_NODES * 4);
    float*    f_n    = (float*)   alloc((size_t)N_NODES * 4);
    float*    logits = (float*)   alloc((size_t)N_TOT * 4);
    unsigned* mx     = (unsigned*)alloc((size_t)N_NODES * 4);
    int*      cnt    = (int*)     alloc((size_t)N_NODES * 4);
    int*      cur    = (int*)     alloc((size_t)N_NODES * 4);
    int*      ptr    = (int*)     alloc((size_t)(N_NODES + 1) * 4);
    int*      idx    = (int*)     alloc((size_t)N_TOT * 4);
    double*   csum   = (double*)  alloc(256 * 8);
    double*   csq    = (double*)  alloc(256 * 8);

    const int EB = (N_TOT + 255) / 256;          // edge-parallel blocks
    const int GB = (N_NODES + 7) / 8;            // gemm blocks (8 rows each)
    const int ND = (N_NODES * 64 + 255) / 256;   // node_dots blocks (wave/node)

    // ---- CSR build (edge list identical for both layers) ----
    hipMemsetAsync(cnt, 0, (size_t)N_NODES * 4, stream);
    hipMemsetAsync(cur, 0, (size_t)N_NODES * 4, stream);
    csr_count<<<EB, 256, 0, stream>>>(ei, cnt);
    exclusive_scan<<<1, 1024, 0, stream>>>(cnt, ptr);
    csr_fill<<<EB, 256, 0, stream>>>(ei, ptr, cur, idx);

    // ---- Layer 1: 64 -> 128 ----
    gemm_rows<64, 128, 8><<<GB, 128, 0, stream>>>(emb, W1, nullptr, bufA, N_NODES);
    node_dots<128><<<ND, 256, 0, stream>>>(bufA, as1, ad1, e_n, f_n);
    hipMemsetAsync(mx, 0, (size_t)N_NODES * 4, stream);
    edge_logits_max<<<EB, 256, 0, stream>>>(ei, e_n, f_n, logits, mx);
    aggregate<128><<<N_NODES, 128, 0, stream>>>(bufA, ei, ptr, idx, logits, mx, b1, x1);
    hipMemsetAsync(csum, 0, 256 * 8, stream);
    hipMemsetAsync(csq,  0, 256 * 8, stream);
    bn_stats<128><<<128, 128, 0, stream>>>(x1, csum, csq);
    bn_apply<128><<<(N_NODES * 128 + 255) / 256, 256, 0, stream>>>(x1, csum, csq, g1, be1);

    // ---- Layer 2: 128 -> 256 ----
    gemm_rows<128, 256, 8><<<GB, 256, 0, stream>>>(x1, W2, nullptr, bufA, N_NODES);
    node_dots<256><<<ND, 256, 0, stream>>>(bufA, as2, ad2, e_n, f_n);
    hipMemsetAsync(mx, 0, (size_t)N_NODES * 4, stream);
    edge_logits_max<<<EB, 256, 0, stream>>>(ei, e_n, f_n, logits, mx);
    aggregate<256><<<N_NODES, 256, 0, stream>>>(bufA, ei, ptr, idx, logits, mx, b2, out);
    hipMemsetAsync(csum, 0, 256 * 8, stream);
    hipMemsetAsync(csq,  0, 256 * 8, stream);
    bn_stats<256><<<128, 256, 0, stream>>>(out, csum, csq);
    bn_apply<256><<<(N_NODES * 256 + 255) / 256, 256, 0, stream>>>(out, csum, csq, g2, be2);

    // ---- Final linear 256 -> 256, in place in d_out ----
    gemm_rows<256, 256, 8><<<GB, 256, 0, stream>>>(out, Wf, bf, out, N_NODES);
}

// Round 2
// 1060.951 us; speedup vs baseline: 1.2288x; 1.2288x over previous
//
#include <hip/hip_runtime.h>
#include <hip/hip_fp16.h>
#include <math.h>

#define N_NODES 50000
#define N_EDGES 800000
#define N_TOT   850000   // E + N self-loops
#define EPS_BN  1e-5f
#define GAT_SLOPE 0.2f
#define ACT_SLOPE 0.01f

// ---- monotone float<->uint encoding for atomicMax on floats ----
__device__ __forceinline__ unsigned enc_f32(float f) {
    unsigned b = __float_as_uint(f);
    return (b & 0x80000000u) ? ~b : (b | 0x80000000u);
}
__device__ __forceinline__ float dec_f32(unsigned u) {
    unsigned b = (u & 0x80000000u) ? (u ^ 0x80000000u) : ~u;
    return __uint_as_float(b);
}

__device__ __forceinline__ void store_val(float* p, float v) { *p = v; }
__device__ __forceinline__ void store_val(__half* p, float v) { *p = __float2half(v); }

// ---- GEMM: out[n x C] = x[n x K] @ W[K x C] (+bias). blockDim == C. ----
// ROWS rows per block staged in LDS; safe for in-place (reads staged before writes).
template<int K, int C, int ROWS, typename OutT>
__global__ void gemm_rows(const float* __restrict__ x, const float* __restrict__ W,
                          const float* __restrict__ bias, OutT* __restrict__ out, int n) {
    __shared__ float xs[ROWS * K];
    const int row0 = blockIdx.x * ROWS;
    const int t = threadIdx.x;
    for (int i = t; i < ROWS * K; i += C) {
        int r = i / K;
        xs[i] = (row0 + r < n) ? x[(size_t)row0 * K + i] : 0.f;
    }
    __syncthreads();
    float acc[ROWS];
#pragma unroll
    for (int r = 0; r < ROWS; ++r) acc[r] = 0.f;
    for (int k = 0; k < K; ++k) {
        float w = W[(size_t)k * C + t];
#pragma unroll
        for (int r = 0; r < ROWS; ++r) acc[r] += xs[r * K + k] * w;
    }
    float b = bias ? bias[t] : 0.f;
#pragma unroll
    for (int r = 0; r < ROWS; ++r)
        if (row0 + r < n) store_val(&out[(size_t)(row0 + r) * C + t], acc[r] + b);
}

// ---- per-node attention dots: e[n]=h[n]·a_s, f[n]=h[n]·a_d. one wave/node ----
// h stored as half2 pairs, C2 = C/2
template<int C2>
__global__ void node_dots(const __half2* __restrict__ h, const float* __restrict__ a_s,
                          const float* __restrict__ a_d, float* __restrict__ e_n,
                          float* __restrict__ f_n) {
    int node = (int)((blockIdx.x * (size_t)blockDim.x + threadIdx.x) >> 6);
    int lane = threadIdx.x & 63;
    if (node >= N_NODES) return;
    float es = 0.f, fs = 0.f;
    for (int c = lane; c < C2; c += 64) {
        float2 v = __half22float2(h[(size_t)node * C2 + c]);
        es += v.x * a_s[2 * c] + v.y * a_s[2 * c + 1];
        fs += v.x * a_d[2 * c] + v.y * a_d[2 * c + 1];
    }
    for (int off = 32; off > 0; off >>= 1) {
        es += __shfl_down(es, off, 64);
        fs += __shfl_down(fs, off, 64);
    }
    if (lane == 0) { e_n[node] = es; f_n[node] = fs; }
}

// ---- CSR build over dst ----
__global__ void csr_count(const int* __restrict__ ei, int* __restrict__ cnt) {
    int e = blockIdx.x * blockDim.x + threadIdx.x;
    if (e >= N_TOT) return;
    int d = (e < N_EDGES) ? ei[N_EDGES + e] : (e - N_EDGES);
    atomicAdd(&cnt[d], 1);
}

// single-block, wave-shuffle scan (3 barriers per 1024-tile)
__global__ void exclusive_scan(const int* __restrict__ cnt, int* __restrict__ ptr) {
    __shared__ int wsum[16];
    __shared__ int s_running;
    int t = threadIdx.x;
    int lane = t & 63, w = t >> 6;
    if (t == 0) s_running = 0;
    __syncthreads();
    for (int base = 0; base < N_NODES; base += 1024) {
        int v = (base + t < N_NODES) ? cnt[base + t] : 0;
        int x = v;
#pragma unroll
        for (int off = 1; off < 64; off <<= 1) {
            int y = __shfl_up(x, off, 64);
            if (lane >= off) x += y;
        }
        if (lane == 63) wsum[w] = x;
        __syncthreads();
        if (t == 0) {
            int s = 0;
#pragma unroll
            for (int i = 0; i < 16; ++i) { int tmp = wsum[i]; wsum[i] = s; s += tmp; }
        }
        __syncthreads();
        int incl = x + wsum[w];
        if (base + t < N_NODES) ptr[base + t] = s_running + incl - v;
        __syncthreads();
        if (t == 1023) s_running = s_running + incl;  // last thread holds tile total
        __syncthreads();
    }
    if (t == 0) ptr[N_NODES] = s_running;
}

__global__ void csr_fill(const int* __restrict__ ei, const int* __restrict__ ptr,
                         int* __restrict__ cur, int* __restrict__ idx) {
    int e = blockIdx.x * blockDim.x + threadIdx.x;
    if (e >= N_TOT) return;
    int d = (e < N_EDGES) ? ei[N_EDGES + e] : (e - N_EDGES);
    int pos = ptr[d] + atomicAdd(&cur[d], 1);
    idx[pos] = e;
}

// ---- edge logits + segment max over dst ----
__global__ void edge_logits_max(const int* __restrict__ ei, const float* __restrict__ e_n,
                                const float* __restrict__ f_n, float* __restrict__ logits,
                                unsigned* __restrict__ mx) {
    int e = blockIdx.x * blockDim.x + threadIdx.x;
    if (e >= N_TOT) return;
    int s, d;
    if (e < N_EDGES) { s = ei[e]; d = ei[N_EDGES + e]; }
    else { s = e - N_EDGES; d = s; }
    float lg = e_n[s] + f_n[d];
    lg = lg > 0.f ? lg : GAT_SLOPE * lg;
    logits[e] = lg;
    atomicMax(&mx[d], enc_f32(lg));
}

// ---- softmax-weighted gather aggregation: block per dst node, blockDim == C/2 ----
// h is half2-packed; each thread owns 2 channels; writes float2.
template<int C2>
__global__ void aggregate(const __half2* __restrict__ h, const int* __restrict__ ei,
                          const int* __restrict__ ptr, const int* __restrict__ idx,
                          const float* __restrict__ logits, const unsigned* __restrict__ mx,
                          const float* __restrict__ bias, float2* __restrict__ out) {
    int d = blockIdx.x;
    int t = threadIdx.x;
    float m = dec_f32(mx[d]);
    int b0 = ptr[d], b1 = ptr[d + 1];
    float ax = 0.f, ay = 0.f, den = 0.f;
    for (int j = b0; j < b1; ++j) {
        int g = idx[j];
        int s = (g < N_EDGES) ? ei[g] : (g - N_EDGES);
        float ex = __expf(logits[g] - m);
        float2 v = __half22float2(h[(size_t)s * C2 + t]);
        ax += ex * v.x;
        ay += ex * v.y;
        den += ex;   // identical across threads (self-loop guarantees den>0)
    }
    float inv = 1.f / den;
    out[(size_t)d * C2 + t] = make_float2(ax * inv + bias[2 * t],
                                          ay * inv + bias[2 * t + 1]);
}

// ---- BatchNorm stats: column partial sums (blockDim == C), f64 atomics ----
template<int C>
__global__ void bn_stats(const float* __restrict__ x, double* __restrict__ sum,
                         double* __restrict__ sumsq) {
    int t = threadIdx.x;
    double s = 0., q = 0.;
    for (int r = blockIdx.x; r < N_NODES; r += gridDim.x) {
        float v = x[(size_t)r * C + t];
        s += v;
        q += (double)v * v;
    }
    atomicAdd(&sum[t], s);
    atomicAdd(&sumsq[t], q);
}

template<int C>
__global__ void bn_apply(float* __restrict__ x, const double* __restrict__ sum,
                         const double* __restrict__ sumsq, const float* __restrict__ gamma,
                         const float* __restrict__ beta) {
    size_t i = (size_t)blockIdx.x * blockDim.x + threadIdx.x;
    if (i >= (size_t)N_NODES * C) return;
    int c = (int)(i % C);
    float mu = (float)(sum[c] / N_NODES);
    float var = (float)(sumsq[c] / N_NODES) - mu * mu;
    float v = x[i];
    float y = (v - mu) * rsqrtf(var + EPS_BN) * gamma[c] + beta[c];
    y = y > 0.f ? y : ACT_SLOPE * y;
    x[i] = y;
}

extern "C" void kernel_launch(void* const* d_in, const int* in_sizes, int n_in,
                              void* d_out, int out_size, void* d_ws, size_t ws_size,
                              hipStream_t stream) {
    const float* emb  = (const float*)d_in[0];
    const int*   ei   = (const int*)  d_in[1];
    const float* W1   = (const float*)d_in[2];
    const float* as1  = (const float*)d_in[3];
    const float* ad1  = (const float*)d_in[4];
    const float* b1   = (const float*)d_in[5];
    const float* g1   = (const float*)d_in[6];
    const float* be1  = (const float*)d_in[7];
    const float* W2   = (const float*)d_in[8];
    const float* as2  = (const float*)d_in[9];
    const float* ad2  = (const float*)d_in[10];
    const float* b2   = (const float*)d_in[11];
    const float* g2   = (const float*)d_in[12];
    const float* be2  = (const float*)d_in[13];
    const float* Wf   = (const float*)d_in[14];
    const float* bf   = (const float*)d_in[15];
    float* out = (float*)d_out;

    char* w = (char*)d_ws;
    auto alloc = [&](size_t bytes) {
        char* p = w;
        w += (bytes + 255) & ~(size_t)255;
        return (void*)p;
    };
    __half*   hbuf   = (__half*)  alloc((size_t)N_NODES * 256 * 2); // h1 then h2 (fp16)
    float*    x1     = (float*)   alloc((size_t)N_NODES * 128 * 4);
    float*    e_n    = (float*)   alloc((size_t)N_NODES * 4);
    float*    f_n    = (float*)   alloc((size_t)N_NODES * 4);
    float*    logits = (float*)   alloc((size_t)N_TOT * 4);
    unsigned* mx     = (unsigned*)alloc((size_t)N_NODES * 4);
    int*      cnt    = (int*)     alloc((size_t)N_NODES * 4);
    int*      cur    = (int*)     alloc((size_t)N_NODES * 4);
    int*      ptr    = (int*)     alloc((size_t)(N_NODES + 1) * 4);
    int*      idx    = (int*)     alloc((size_t)N_TOT * 4);
    double*   csum   = (double*)  alloc(256 * 8);
    double*   csq    = (double*)  alloc(256 * 8);

    const int EB  = (N_TOT + 255) / 256;          // edge-parallel blocks
    const int GB  = (N_NODES + 15) / 16;          // gemm blocks (16 rows each)
    const int ND  = (N_NODES * 64 + 255) / 256;   // node_dots blocks (wave/node)

    // ---- CSR build (edge list identical for both layers) ----
    hipMemsetAsync(cnt, 0, (size_t)N_NODES * 4, stream);
    hipMemsetAsync(cur, 0, (size_t)N_NODES * 4, stream);
    csr_count<<<EB, 256, 0, stream>>>(ei, cnt);
    exclusive_scan<<<1, 1024, 0, stream>>>(cnt, ptr);
    csr_fill<<<EB, 256, 0, stream>>>(ei, ptr, cur, idx);

    // ---- Layer 1: 64 -> 128 ----
    gemm_rows<64, 128, 16, __half><<<GB, 128, 0, stream>>>(emb, W1, nullptr, hbuf, N_NODES);
    node_dots<64><<<ND, 256, 0, stream>>>((const __half2*)hbuf, as1, ad1, e_n, f_n);
    hipMemsetAsync(mx, 0, (size_t)N_NODES * 4, stream);
    edge_logits_max<<<EB, 256, 0, stream>>>(ei, e_n, f_n, logits, mx);
    aggregate<64><<<N_NODES, 64, 0, stream>>>((const __half2*)hbuf, ei, ptr, idx, logits, mx,
                                              b1, (float2*)x1);
    hipMemsetAsync(csum, 0, 256 * 8, stream);
    hipMemsetAsync(csq,  0, 256 * 8, stream);
    bn_stats<128><<<128, 128, 0, stream>>>(x1, csum, csq);
    bn_apply<128><<<(N_NODES * 128 + 255) / 256, 256, 0, stream>>>(x1, csum, csq, g1, be1);

    // ---- Layer 2: 128 -> 256 ----
    gemm_rows<128, 256, 16, __half><<<GB, 256, 0, stream>>>(x1, W2, nullptr, hbuf, N_NODES);
    node_dots<128><<<ND, 256, 0, stream>>>((const __half2*)hbuf, as2, ad2, e_n, f_n);
    hipMemsetAsync(mx, 0, (size_t)N_NODES * 4, stream);
    edge_logits_max<<<EB, 256, 0, stream>>>(ei, e_n, f_n, logits, mx);
    aggregate<128><<<N_NODES, 128, 0, stream>>>((const __half2*)hbuf, ei, ptr, idx, logits, mx,
                                                b2, (float2*)out);
    hipMemsetAsync(csum, 0, 256 * 8, stream);
    hipMemsetAsync(csq,  0, 256 * 8, stream);
    bn_stats<256><<<128, 256, 0, stream>>>(out, csum, csq);
    bn_apply<256><<<(N_NODES * 256 + 255) / 256, 256, 0, stream>>>(out, csum, csq, g2, be2);

    // ---- Final linear 256 -> 256, in place in d_out ----
    gemm_rows<256, 256, 16, float><<<GB, 256, 0, stream>>>(out, Wf, bf, out, N_NODES);
}

// Round 3
// 656.703 us; speedup vs baseline: 1.9852x; 1.6156x over previous
//
#include <hip/hip_runtime.h>
#include <hip/hip_fp16.h>
#include <math.h>

#define N_NODES 50000
#define N_EDGES 800000
#define N_TOT   850000   // E + N self-loops
#define EPS_BN  1e-5f
#define GAT_SLOPE 0.2f
#define ACT_SLOPE 0.01f
#define SCAN_T   1024
#define N_TILES  ((N_NODES + SCAN_T - 1) / SCAN_T)   // 49

__device__ __forceinline__ float wred_max(float x) {
#pragma unroll
    for (int m = 32; m; m >>= 1) x = fmaxf(x, __shfl_xor(x, m, 64));
    return x;
}
__device__ __forceinline__ float wred_sum(float x) {
#pragma unroll
    for (int m = 32; m; m >>= 1) x += __shfl_xor(x, m, 64);
    return x;
}

__device__ __forceinline__ void store_val(float* p, float v) { *p = v; }
__device__ __forceinline__ void store_val(__half* p, float v) { *p = __float2half(v); }

// ---- GEMM: out[n x C] = act(bn(x))[n x K] @ W[K x C] (+bias). blockDim == C. ----
// ROWS rows staged in LDS. If scale!=nullptr, applies y=x*scale[c]+shift[c]; lrelu
// during staging (fused BatchNorm+LeakyReLU on the INPUT). In-place safe.
template<int K, int C, int ROWS, typename OutT>
__global__ void gemm_rows(const float* __restrict__ x, const float* __restrict__ W,
                          const float* __restrict__ bias, OutT* __restrict__ out, int n,
                          const float* __restrict__ scale, const float* __restrict__ shift) {
    __shared__ float xs[ROWS * K];
    const int row0 = blockIdx.x * ROWS;
    const int t = threadIdx.x;
    for (int i = t; i < ROWS * K; i += C) {
        int r = i / K, c = i - r * K;
        float v = (row0 + r < n) ? x[(size_t)row0 * K + i] : 0.f;
        if (scale) {
            v = v * scale[c] + shift[c];
            v = v > 0.f ? v : ACT_SLOPE * v;
        }
        xs[i] = v;
    }
    __syncthreads();
    float acc[ROWS];
#pragma unroll
    for (int r = 0; r < ROWS; ++r) acc[r] = 0.f;
    for (int k = 0; k < K; ++k) {
        float w = W[(size_t)k * C + t];
#pragma unroll
        for (int r = 0; r < ROWS; ++r) acc[r] += xs[r * K + k] * w;
    }
    float b = bias ? bias[t] : 0.f;
#pragma unroll
    for (int r = 0; r < ROWS; ++r)
        if (row0 + r < n) store_val(&out[(size_t)(row0 + r) * C + t], acc[r] + b);
}

// ---- per-node attention dots: e[n]=h[n]·a_s, f[n]=h[n]·a_d. one wave/node ----
template<int C2>
__global__ void node_dots(const __half2* __restrict__ h, const float* __restrict__ a_s,
                          const float* __restrict__ a_d, float* __restrict__ e_n,
                          float* __restrict__ f_n) {
    int node = (int)((blockIdx.x * (size_t)blockDim.x + threadIdx.x) >> 6);
    int lane = threadIdx.x & 63;
    if (node >= N_NODES) return;
    float es = 0.f, fs = 0.f;
    for (int c = lane; c < C2; c += 64) {
        float2 v = __half22float2(h[(size_t)node * C2 + c]);
        es += v.x * a_s[2 * c] + v.y * a_s[2 * c + 1];
        fs += v.x * a_d[2 * c] + v.y * a_d[2 * c + 1];
    }
    es = wred_sum(es);
    fs = wred_sum(fs);
    if (lane == 0) { e_n[node] = es; f_n[node] = fs; }
}

// ---- CSR build over dst ----
__global__ void csr_count(const int* __restrict__ ei, int* __restrict__ cnt) {
    int e = blockIdx.x * blockDim.x + threadIdx.x;
    if (e >= N_TOT) return;
    int d = (e < N_EDGES) ? ei[N_EDGES + e] : (e - N_EDGES);
    atomicAdd(&cnt[d], 1);
}

// ---- device-wide exclusive scan over cnt[N_NODES] -> ptr ----
__global__ void scan_phase1(const int* __restrict__ cnt, int* __restrict__ ptr,
                            int* __restrict__ tsum) {
    __shared__ int wsum[16];
    int base = blockIdx.x * SCAN_T;
    int t = threadIdx.x, lane = t & 63, w = t >> 6;
    int v = (base + t < N_NODES) ? cnt[base + t] : 0;
    int x = v;
#pragma unroll
    for (int off = 1; off < 64; off <<= 1) {
        int y = __shfl_up(x, off, 64);
        if (lane >= off) x += y;
    }
    if (lane == 63) wsum[w] = x;
    __syncthreads();
    if (t == 0) {
        int s = 0;
#pragma unroll
        for (int i = 0; i < 16; ++i) { int tmp = wsum[i]; wsum[i] = s; s += tmp; }
    }
    __syncthreads();
    int incl = x + wsum[w];
    if (base + t < N_NODES) ptr[base + t] = incl - v;   // tile-local exclusive
    if (t == SCAN_T - 1) tsum[blockIdx.x] = incl;
}

__global__ void scan_phase2(const int* __restrict__ tsum, int* __restrict__ toff,
                            int* __restrict__ ptr) {
    int t = threadIdx.x;                       // 64 threads, N_TILES <= 64
    int v = (t < N_TILES) ? tsum[t] : 0;
    int x = v;
#pragma unroll
    for (int off = 1; off < 64; off <<= 1) {
        int y = __shfl_up(x, off, 64);
        if (t >= off) x += y;
    }
    if (t < N_TILES) toff[t] = x - v;
    if (t == 63) ptr[N_NODES] = x;             // grand total
}

__global__ void scan_phase3(int* __restrict__ ptr, const int* __restrict__ toff) {
    int i = blockIdx.x * SCAN_T + threadIdx.x;
    if (i < N_NODES) ptr[i] += toff[blockIdx.x];
}

// stores SOURCE NODE (not edge id) in CSR slot — removes one indirection downstream
__global__ void csr_fill_src(const int* __restrict__ ei, const int* __restrict__ ptr,
                             int* __restrict__ cur, int* __restrict__ srcs) {
    int e = blockIdx.x * blockDim.x + threadIdx.x;
    if (e >= N_TOT) return;
    int s, d;
    if (e < N_EDGES) { s = ei[e]; d = ei[N_EDGES + e]; }
    else { s = e - N_EDGES; d = s; }
    int pos = ptr[d] + atomicAdd(&cur[d], 1);
    srcs[pos] = s;
}

// ---- per-dst softmax weights, CSR order, pre-normalized. one wave per dst ----
__global__ void attn_w(const int* __restrict__ srcs, const int* __restrict__ ptr,
                       const float* __restrict__ e_n, const float* __restrict__ f_n,
                       float* __restrict__ wc) {
    int d = blockIdx.x * 4 + (threadIdx.x >> 6);
    int lane = threadIdx.x & 63;
    if (d >= N_NODES) return;
    int b0 = ptr[d], b1 = ptr[d + 1];
    float fd = f_n[d];
    float mymax = -1e30f;
    for (int j = b0 + lane; j < b1; j += 64) {
        float lg = e_n[srcs[j]] + fd;
        lg = lg > 0.f ? lg : GAT_SLOPE * lg;
        wc[j] = lg;
        mymax = fmaxf(mymax, lg);
    }
    float m = wred_max(mymax);
    float myden = 0.f;
    for (int j = b0 + lane; j < b1; j += 64) {
        float ex = __expf(wc[j] - m);
        wc[j] = ex;
        myden += ex;
    }
    float inv = 1.f / wred_sum(myden);
    for (int j = b0 + lane; j < b1; j += 64) wc[j] *= inv;
}

// ---- weighted gather aggregation: block per dst, blockDim == C/2, 4x unrolled ----
template<int C2>
__global__ void aggregate(const __half2* __restrict__ h, const int* __restrict__ srcs,
                          const float* __restrict__ wc, const int* __restrict__ ptr,
                          const float* __restrict__ bias, float2* __restrict__ out) {
    int d = blockIdx.x;
    int t = threadIdx.x;
    int b0 = ptr[d], b1 = ptr[d + 1];
    float ax = 0.f, ay = 0.f;
    int j = b0;
    for (; j + 4 <= b1; j += 4) {
        int s0 = srcs[j], s1 = srcs[j + 1], s2 = srcs[j + 2], s3 = srcs[j + 3];
        float w0 = wc[j], w1 = wc[j + 1], w2 = wc[j + 2], w3 = wc[j + 3];
        float2 v0 = __half22float2(h[(size_t)s0 * C2 + t]);
        float2 v1 = __half22float2(h[(size_t)s1 * C2 + t]);
        float2 v2 = __half22float2(h[(size_t)s2 * C2 + t]);
        float2 v3 = __half22float2(h[(size_t)s3 * C2 + t]);
        ax += w0 * v0.x + w1 * v1.x + w2 * v2.x + w3 * v3.x;
        ay += w0 * v0.y + w1 * v1.y + w2 * v2.y + w3 * v3.y;
    }
    for (; j < b1; ++j) {
        float w = wc[j];
        float2 v = __half22float2(h[(size_t)srcs[j] * C2 + t]);
        ax += w * v.x;
        ay += w * v.y;
    }
    out[(size_t)d * C2 + t] = make_float2(ax + bias[2 * t], ay + bias[2 * t + 1]);
}

// ---- BatchNorm stats: column partial sums (blockDim == C), f64 atomics ----
template<int C>
__global__ void bn_stats(const float* __restrict__ x, double* __restrict__ sum,
                         double* __restrict__ sumsq) {
    int t = threadIdx.x;
    double s = 0., q = 0.;
    for (int r = blockIdx.x; r < N_NODES; r += gridDim.x) {
        float v = x[(size_t)r * C + t];
        s += v;
        q += (double)v * v;
    }
    atomicAdd(&sum[t], s);
    atomicAdd(&sumsq[t], q);
}

// per-column scale/shift so BN+LeakyReLU can fuse into the next GEMM's staging
template<int C>
__global__ void bn_coef(const double* __restrict__ sum, const double* __restrict__ sumsq,
                        const float* __restrict__ gamma, const float* __restrict__ beta,
                        float* __restrict__ scale, float* __restrict__ shift) {
    int c = threadIdx.x;
    float mu = (float)(sum[c] / N_NODES);
    float var = (float)(sumsq[c] / N_NODES) - mu * mu;
    float sc = gamma[c] * rsqrtf(var + EPS_BN);
    scale[c] = sc;
    shift[c] = beta[c] - mu * sc;
}

extern "C" void kernel_launch(void* const* d_in, const int* in_sizes, int n_in,
                              void* d_out, int out_size, void* d_ws, size_t ws_size,
                              hipStream_t stream) {
    const float* emb  = (const float*)d_in[0];
    const int*   ei   = (const int*)  d_in[1];
    const float* W1   = (const float*)d_in[2];
    const float* as1  = (const float*)d_in[3];
    const float* ad1  = (const float*)d_in[4];
    const float* b1   = (const float*)d_in[5];
    const float* g1   = (const float*)d_in[6];
    const float* be1  = (const float*)d_in[7];
    const float* W2   = (const float*)d_in[8];
    const float* as2  = (const float*)d_in[9];
    const float* ad2  = (const float*)d_in[10];
    const float* b2   = (const float*)d_in[11];
    const float* g2   = (const float*)d_in[12];
    const float* be2  = (const float*)d_in[13];
    const float* Wf   = (const float*)d_in[14];
    const float* bf   = (const float*)d_in[15];
    float* out = (float*)d_out;

    char* w = (char*)d_ws;
    auto alloc = [&](size_t bytes) {
        char* p = w;
        w += (bytes + 255) & ~(size_t)255;
        return (void*)p;
    };
    __half* hbuf = (__half*)alloc((size_t)N_NODES * 256 * 2);  // h1 then h2 (fp16)
    float*  x1   = (float*) alloc((size_t)N_NODES * 128 * 4);
    float*  e_n  = (float*) alloc((size_t)N_NODES * 4);
    float*  f_n  = (float*) alloc((size_t)N_NODES * 4);
    float*  wc   = (float*) alloc((size_t)N_TOT * 4);          // csr-ordered weights
    int*    srcs = (int*)   alloc((size_t)N_TOT * 4);
    int*    cnt  = (int*)   alloc((size_t)N_NODES * 4);
    int*    cur  = (int*)   alloc((size_t)N_NODES * 4);
    int*    ptr  = (int*)   alloc((size_t)(N_NODES + 1) * 4);
    int*    tsum = (int*)   alloc((size_t)N_TILES * 4);
    int*    toff = (int*)   alloc((size_t)N_TILES * 4);
    double* csum = (double*)alloc(256 * 8);
    double* csq  = (double*)alloc(256 * 8);
    float*  sc1  = (float*) alloc(128 * 4);
    float*  sh1  = (float*) alloc(128 * 4);
    float*  sc2  = (float*) alloc(256 * 4);
    float*  sh2  = (float*) alloc(256 * 4);

    const int EB = (N_TOT + 255) / 256;
    const int GB = (N_NODES + 15) / 16;
    const int ND = (N_NODES * 64 + 255) / 256;
    const int AW = (N_NODES + 3) / 4;

    // ---- CSR build (shared by both layers) ----
    hipMemsetAsync(cnt, 0, (size_t)N_NODES * 4, stream);
    hipMemsetAsync(cur, 0, (size_t)N_NODES * 4, stream);
    csr_count<<<EB, 256, 0, stream>>>(ei, cnt);
    scan_phase1<<<N_TILES, SCAN_T, 0, stream>>>(cnt, ptr, tsum);
    scan_phase2<<<1, 64, 0, stream>>>(tsum, toff, ptr);
    scan_phase3<<<N_TILES, SCAN_T, 0, stream>>>(ptr, toff);
    csr_fill_src<<<EB, 256, 0, stream>>>(ei, ptr, cur, srcs);

    // ---- Layer 1: 64 -> 128 ----
    gemm_rows<64, 128, 16, __half><<<GB, 128, 0, stream>>>(emb, W1, nullptr, hbuf, N_NODES,
                                                           nullptr, nullptr);
    node_dots<64><<<ND, 256, 0, stream>>>((const __half2*)hbuf, as1, ad1, e_n, f_n);
    attn_w<<<AW, 256, 0, stream>>>(srcs, ptr, e_n, f_n, wc);
    aggregate<64><<<N_NODES, 64, 0, stream>>>((const __half2*)hbuf, srcs, wc, ptr, b1,
                                              (float2*)x1);
    hipMemsetAsync(csum, 0, 256 * 8, stream);
    hipMemsetAsync(csq,  0, 256 * 8, stream);
    bn_stats<128><<<400, 128, 0, stream>>>(x1, csum, csq);
    bn_coef<128><<<1, 128, 0, stream>>>(csum, csq, g1, be1, sc1, sh1);

    // ---- Layer 2: 128 -> 256 (BN1+lrelu fused into staging) ----
    gemm_rows<128, 256, 16, __half><<<GB, 256, 0, stream>>>(x1, W2, nullptr, hbuf, N_NODES,
                                                            sc1, sh1);
    node_dots<128><<<ND, 256, 0, stream>>>((const __half2*)hbuf, as2, ad2, e_n, f_n);
    attn_w<<<AW, 256, 0, stream>>>(srcs, ptr, e_n, f_n, wc);
    aggregate<128><<<N_NODES, 128, 0, stream>>>((const __half2*)hbuf, srcs, wc, ptr, b2,
                                                (float2*)out);
    hipMemsetAsync(csum, 0, 256 * 8, stream);
    hipMemsetAsync(csq,  0, 256 * 8, stream);
    bn_stats<256><<<400, 256, 0, stream>>>(out, csum, csq);
    bn_coef<256><<<1, 256, 0, stream>>>(csum, csq, g2, be2, sc2, sh2);

    // ---- Final linear 256 -> 256, in place, BN2+lrelu fused into staging ----
    gemm_rows<256, 256, 16, float><<<GB, 256, 0, stream>>>(out, Wf, bf, out, N_NODES,
                                                           sc2, sh2);
}

// Round 4
// 558.220 us; speedup vs baseline: 2.3354x; 1.1764x over previous
//
#include <hip/hip_runtime.h>
#include <hip/hip_fp16.h>
#include <math.h>

#define N_NODES 50000
#define N_EDGES 800000
#define N_TOT   850000   // E + N self-loops
#define EPS_BN  1e-5f
#define GAT_SLOPE 0.2f
#define ACT_SLOPE 0.01f
#define SCAN_T   1024
#define N_TILES  ((N_NODES + SCAN_T - 1) / SCAN_T)   // 49

typedef _Float16 half8_t __attribute__((ext_vector_type(8)));
typedef _Float16 half4_t __attribute__((ext_vector_type(4)));
typedef float    f32x4   __attribute__((ext_vector_type(4)));

__device__ __forceinline__ float wred_max(float x) {
#pragma unroll
    for (int m = 32; m; m >>= 1) x = fmaxf(x, __shfl_xor(x, m, 64));
    return x;
}
__device__ __forceinline__ float wred_sum(float x) {
#pragma unroll
    for (int m = 32; m; m >>= 1) x += __shfl_xor(x, m, 64);
    return x;
}

__device__ __forceinline__ void store_val(float* p, float v) { *p = v; }
__device__ __forceinline__ void store_val(_Float16* p, float v) { *p = (_Float16)v; }

// ---- transpose + fp16-cast of W[K x C] -> Wt[C x K] ----
template<int K, int C>
__global__ void wcast_t(const float* __restrict__ W, _Float16* __restrict__ wt) {
    int i = blockIdx.x * 256 + threadIdx.x;
    if (i >= K * C) return;
    int k = i / C, c = i - k * C;          // coalesced read of W
    wt[(size_t)c * K + k] = (_Float16)W[i];
}

// ---- MFMA GEMM: out[n x C] = act(bn(x))[n x K] @ W[K x C] (+bias) ----
// 256 thr = 4 waves; 64 rows/block. x fp32 staged to LDS fp16 (padded rows).
// Wt is W^T fp16 [C x K] so B-fragments are contiguous. Optional fused
// per-column BN scale/shift + LeakyReLU on the INPUT during staging.
// Fragment layouts (verified m89/m120): A[m=lane&15][k=quad*8+j],
// B[k=quad*8+j][n=lane&15], C/D col=lane&15 row=quad*4+reg.
template<int K, int C, typename OutT>
__global__ __launch_bounds__(256) void
gemm_mfma(const float* __restrict__ x, const _Float16* __restrict__ wt,
          const float* __restrict__ bias, OutT* __restrict__ out, int n,
          const float* __restrict__ scale, const float* __restrict__ shift) {
    constexpr int LK = K + 8;              // +16B pad: conflict-free quad ds_read_b128
    __shared__ _Float16 xs[64 * LK];
    const int row0 = blockIdx.x * 64;
    const int t = threadIdx.x;

    // stage 64 x K fp32 -> fp16 LDS (4 elems/thread/iter)
    for (int i = t * 4; i < 64 * K; i += 256 * 4) {
        int r = i / K, c = i - (i / K) * K;
        float4 v = make_float4(0.f, 0.f, 0.f, 0.f);
        if (row0 + r < n) v = *(const float4*)&x[(size_t)(row0 + r) * K + c];
        if (scale) {
            v.x = v.x * scale[c] + shift[c];     v.x = v.x > 0.f ? v.x : ACT_SLOPE * v.x;
            v.y = v.y * scale[c + 1] + shift[c + 1]; v.y = v.y > 0.f ? v.y : ACT_SLOPE * v.y;
            v.z = v.z * scale[c + 2] + shift[c + 2]; v.z = v.z > 0.f ? v.z : ACT_SLOPE * v.z;
            v.w = v.w * scale[c + 3] + shift[c + 3]; v.w = v.w > 0.f ? v.w : ACT_SLOPE * v.w;
        }
        half4_t h4 = { (_Float16)v.x, (_Float16)v.y, (_Float16)v.z, (_Float16)v.w };
        *(half4_t*)&xs[r * LK + c] = h4;
    }
    __syncthreads();

    const int w = t >> 6, l = t & 63;
    const int l16 = l & 15, quad = l >> 4;
    const _Float16* arow = &xs[(16 * w + l16) * LK + quad * 8];

    for (int c0 = 0; c0 < C; c0 += 64) {
        f32x4 acc[4] = {};
        for (int k0 = 0; k0 < K; k0 += 32) {
            half8_t a = *(const half8_t*)(arow + k0);
#pragma unroll
            for (int tt = 0; tt < 4; ++tt) {
                const _Float16* bp = &wt[(size_t)(c0 + tt * 16 + l16) * K + k0 + quad * 8];
                half8_t b = *(const half8_t*)bp;
                acc[tt] = __builtin_amdgcn_mfma_f32_16x16x32_f16(a, b, acc[tt], 0, 0, 0);
            }
        }
#pragma unroll
        for (int tt = 0; tt < 4; ++tt) {
            int col = c0 + tt * 16 + l16;
            float bb = bias ? bias[col] : 0.f;
            int rbase = row0 + 16 * w + quad * 4;
#pragma unroll
            for (int i = 0; i < 4; ++i)
                if (rbase + i < n)
                    store_val(&out[(size_t)(rbase + i) * C + col], acc[tt][i] + bb);
        }
    }
}

// ---- per-node attention dots: e[n]=h[n]·a_s, f[n]=h[n]·a_d. one wave/node ----
template<int C2>
__global__ void node_dots(const __half2* __restrict__ h, const float* __restrict__ a_s,
                          const float* __restrict__ a_d, float* __restrict__ e_n,
                          float* __restrict__ f_n) {
    int node = (int)((blockIdx.x * (size_t)blockDim.x + threadIdx.x) >> 6);
    int lane = threadIdx.x & 63;
    if (node >= N_NODES) return;
    float es = 0.f, fs = 0.f;
    for (int c = lane; c < C2; c += 64) {
        float2 v = __half22float2(h[(size_t)node * C2 + c]);
        es += v.x * a_s[2 * c] + v.y * a_s[2 * c + 1];
        fs += v.x * a_d[2 * c] + v.y * a_d[2 * c + 1];
    }
    es = wred_sum(es);
    fs = wred_sum(fs);
    if (lane == 0) { e_n[node] = es; f_n[node] = fs; }
}

// ---- CSR build over dst ----
__global__ void csr_count(const int* __restrict__ ei, int* __restrict__ cnt) {
    int e = blockIdx.x * blockDim.x + threadIdx.x;
    if (e >= N_TOT) return;
    int d = (e < N_EDGES) ? ei[N_EDGES + e] : (e - N_EDGES);
    atomicAdd(&cnt[d], 1);
}

__global__ void scan_phase1(const int* __restrict__ cnt, int* __restrict__ ptr,
                            int* __restrict__ tsum) {
    __shared__ int wsum[16];
    int base = blockIdx.x * SCAN_T;
    int t = threadIdx.x, lane = t & 63, w = t >> 6;
    int v = (base + t < N_NODES) ? cnt[base + t] : 0;
    int x = v;
#pragma unroll
    for (int off = 1; off < 64; off <<= 1) {
        int y = __shfl_up(x, off, 64);
        if (lane >= off) x += y;
    }
    if (lane == 63) wsum[w] = x;
    __syncthreads();
    if (t == 0) {
        int s = 0;
#pragma unroll
        for (int i = 0; i < 16; ++i) { int tmp = wsum[i]; wsum[i] = s; s += tmp; }
    }
    __syncthreads();
    int incl = x + wsum[w];
    if (base + t < N_NODES) ptr[base + t] = incl - v;
    if (t == SCAN_T - 1) tsum[blockIdx.x] = incl;
}

__global__ void scan_phase2(const int* __restrict__ tsum, int* __restrict__ toff,
                            int* __restrict__ ptr) {
    int t = threadIdx.x;
    int v = (t < N_TILES) ? tsum[t] : 0;
    int x = v;
#pragma unroll
    for (int off = 1; off < 64; off <<= 1) {
        int y = __shfl_up(x, off, 64);
        if (t >= off) x += y;
    }
    if (t < N_TILES) toff[t] = x - v;
    if (t == 63) ptr[N_NODES] = x;
}

__global__ void scan_phase3(int* __restrict__ ptr, const int* __restrict__ toff) {
    int i = blockIdx.x * SCAN_T + threadIdx.x;
    if (i < N_NODES) ptr[i] += toff[blockIdx.x];
}

__global__ void csr_fill_src(const int* __restrict__ ei, const int* __restrict__ ptr,
                             int* __restrict__ cur, int* __restrict__ srcs) {
    int e = blockIdx.x * blockDim.x + threadIdx.x;
    if (e >= N_TOT) return;
    int s, d;
    if (e < N_EDGES) { s = ei[e]; d = ei[N_EDGES + e]; }
    else { s = e - N_EDGES; d = s; }
    int pos = ptr[d] + atomicAdd(&cur[d], 1);
    srcs[pos] = s;
}

// ---- per-dst softmax weights, CSR order, pre-normalized. one wave per dst ----
__global__ void attn_w(const int* __restrict__ srcs, const int* __restrict__ ptr,
                       const float* __restrict__ e_n, const float* __restrict__ f_n,
                       float* __restrict__ wc) {
    int d = blockIdx.x * 4 + (threadIdx.x >> 6);
    int lane = threadIdx.x & 63;
    if (d >= N_NODES) return;
    int b0 = ptr[d], b1 = ptr[d + 1];
    float fd = f_n[d];
    float mymax = -1e30f;
    for (int j = b0 + lane; j < b1; j += 64) {
        float lg = e_n[srcs[j]] + fd;
        lg = lg > 0.f ? lg : GAT_SLOPE * lg;
        wc[j] = lg;
        mymax = fmaxf(mymax, lg);
    }
    float m = wred_max(mymax);
    float myden = 0.f;
    for (int j = b0 + lane; j < b1; j += 64) {
        float ex = __expf(wc[j] - m);
        wc[j] = ex;
        myden += ex;
    }
    float inv = 1.f / wred_sum(myden);
    for (int j = b0 + lane; j < b1; j += 64) wc[j] *= inv;
}

// ---- weighted gather aggregation: block per dst, blockDim == C/2, 4x unrolled ----
template<int C2>
__global__ void aggregate(const __half2* __restrict__ h, const int* __restrict__ srcs,
                          const float* __restrict__ wc, const int* __restrict__ ptr,
                          const float* __restrict__ bias, float2* __restrict__ out) {
    int d = blockIdx.x;
    int t = threadIdx.x;
    int b0 = ptr[d], b1 = ptr[d + 1];
    float ax = 0.f, ay = 0.f;
    int j = b0;
    for (; j + 4 <= b1; j += 4) {
        int s0 = srcs[j], s1 = srcs[j + 1], s2 = srcs[j + 2], s3 = srcs[j + 3];
        float w0 = wc[j], w1 = wc[j + 1], w2 = wc[j + 2], w3 = wc[j + 3];
        float2 v0 = __half22float2(h[(size_t)s0 * C2 + t]);
        float2 v1 = __half22float2(h[(size_t)s1 * C2 + t]);
        float2 v2 = __half22float2(h[(size_t)s2 * C2 + t]);
        float2 v3 = __half22float2(h[(size_t)s3 * C2 + t]);
        ax += w0 * v0.x + w1 * v1.x + w2 * v2.x + w3 * v3.x;
        ay += w0 * v0.y + w1 * v1.y + w2 * v2.y + w3 * v3.y;
    }
    for (; j < b1; ++j) {
        float w = wc[j];
        float2 v = __half22float2(h[(size_t)srcs[j] * C2 + t]);
        ax += w * v.x;
        ay += w * v.y;
    }
    out[(size_t)d * C2 + t] = make_float2(ax + bias[2 * t], ay + bias[2 * t + 1]);
}

// ---- BatchNorm stats + fused-coefficient computation ----
template<int C>
__global__ void bn_stats(const float* __restrict__ x, double* __restrict__ sum,
                         double* __restrict__ sumsq) {
    int t = threadIdx.x;
    double s = 0., q = 0.;
    for (int r = blockIdx.x; r < N_NODES; r += gridDim.x) {
        float v = x[(size_t)r * C + t];
        s += v;
        q += (double)v * v;
    }
    atomicAdd(&sum[t], s);
    atomicAdd(&sumsq[t], q);
}

template<int C>
__global__ void bn_coef(const double* __restrict__ sum, const double* __restrict__ sumsq,
                        const float* __restrict__ gamma, const float* __restrict__ beta,
                        float* __restrict__ scale, float* __restrict__ shift) {
    int c = threadIdx.x;
    float mu = (float)(sum[c] / N_NODES);
    float var = (float)(sumsq[c] / N_NODES) - mu * mu;
    float sc = gamma[c] * rsqrtf(var + EPS_BN);
    scale[c] = sc;
    shift[c] = beta[c] - mu * sc;
}

extern "C" void kernel_launch(void* const* d_in, const int* in_sizes, int n_in,
                              void* d_out, int out_size, void* d_ws, size_t ws_size,
                              hipStream_t stream) {
    const float* emb  = (const float*)d_in[0];
    const int*   ei   = (const int*)  d_in[1];
    const float* W1   = (const float*)d_in[2];
    const float* as1  = (const float*)d_in[3];
    const float* ad1  = (const float*)d_in[4];
    const float* b1   = (const float*)d_in[5];
    const float* g1   = (const float*)d_in[6];
    const float* be1  = (const float*)d_in[7];
    const float* W2   = (const float*)d_in[8];
    const float* as2  = (const float*)d_in[9];
    const float* ad2  = (const float*)d_in[10];
    const float* b2   = (const float*)d_in[11];
    const float* g2   = (const float*)d_in[12];
    const float* be2  = (const float*)d_in[13];
    const float* Wf   = (const float*)d_in[14];
    const float* bf   = (const float*)d_in[15];
    float* out = (float*)d_out;

    char* w = (char*)d_ws;
    auto alloc = [&](size_t bytes) {
        char* p = w;
        w += (bytes + 255) & ~(size_t)255;
        return (void*)p;
    };
    _Float16* hbuf = (_Float16*)alloc((size_t)N_NODES * 256 * 2); // h1/h2 fp16
    float*  x1   = (float*) alloc((size_t)N_NODES * 128 * 4);
    float*  e_n  = (float*) alloc((size_t)N_NODES * 4);
    float*  f_n  = (float*) alloc((size_t)N_NODES * 4);
    float*  wc   = (float*) alloc((size_t)N_TOT * 4);
    int*    srcs = (int*)   alloc((size_t)N_TOT * 4);
    int*    cnt  = (int*)   alloc((size_t)N_NODES * 4);
    int*    cur  = (int*)   alloc((size_t)N_NODES * 4);
    int*    ptr  = (int*)   alloc((size_t)(N_NODES + 1) * 4);
    int*    tsum = (int*)   alloc((size_t)N_TILES * 4);
    int*    toff = (int*)   alloc((size_t)N_TILES * 4);
    double* csum = (double*)alloc(256 * 8);
    double* csq  = (double*)alloc(256 * 8);
    float*  sc1  = (float*) alloc(128 * 4);
    float*  sh1  = (float*) alloc(128 * 4);
    float*  sc2  = (float*) alloc(256 * 4);
    float*  sh2  = (float*) alloc(256 * 4);
    _Float16* wt1 = (_Float16*)alloc((size_t)64 * 128 * 2);
    _Float16* wt2 = (_Float16*)alloc((size_t)128 * 256 * 2);
    _Float16* wtf = (_Float16*)alloc((size_t)256 * 256 * 2);

    const int EB   = (N_TOT + 255) / 256;
    const int GB64 = (N_NODES + 63) / 64;
    const int ND   = (N_NODES * 64 + 255) / 256;
    const int AW   = (N_NODES + 3) / 4;

    // ---- weight transpose+cast (small) ----
    wcast_t<64, 128><<<(64 * 128 + 255) / 256, 256, 0, stream>>>(W1, wt1);
    wcast_t<128, 256><<<(128 * 256 + 255) / 256, 256, 0, stream>>>(W2, wt2);
    wcast_t<256, 256><<<(256 * 256 + 255) / 256, 256, 0, stream>>>(Wf, wtf);

    // ---- CSR build (shared by both layers) ----
    hipMemsetAsync(cnt, 0, (size_t)N_NODES * 4, stream);
    hipMemsetAsync(cur, 0, (size_t)N_NODES * 4, stream);
    csr_count<<<EB, 256, 0, stream>>>(ei, cnt);
    scan_phase1<<<N_TILES, SCAN_T, 0, stream>>>(cnt, ptr, tsum);
    scan_phase2<<<1, 64, 0, stream>>>(tsum, toff, ptr);
    scan_phase3<<<N_TILES, SCAN_T, 0, stream>>>(ptr, toff);
    csr_fill_src<<<EB, 256, 0, stream>>>(ei, ptr, cur, srcs);

    // ---- Layer 1: 64 -> 128 ----
    gemm_mfma<64, 128, _Float16><<<GB64, 256, 0, stream>>>(emb, wt1, nullptr, hbuf, N_NODES,
                                                           nullptr, nullptr);
    node_dots<64><<<ND, 256, 0, stream>>>((const __half2*)hbuf, as1, ad1, e_n, f_n);
    attn_w<<<AW, 256, 0, stream>>>(srcs, ptr, e_n, f_n, wc);
    aggregate<64><<<N_NODES, 64, 0, stream>>>((const __half2*)hbuf, srcs, wc, ptr, b1,
                                              (float2*)x1);
    hipMemsetAsync(csum, 0, 256 * 8, stream);
    hipMemsetAsync(csq,  0, 256 * 8, stream);
    bn_stats<128><<<400, 128, 0, stream>>>(x1, csum, csq);
    bn_coef<128><<<1, 128, 0, stream>>>(csum, csq, g1, be1, sc1, sh1);

    // ---- Layer 2: 128 -> 256 (BN1+lrelu fused into staging) ----
    gemm_mfma<128, 256, _Float16><<<GB64, 256, 0, stream>>>(x1, wt2, nullptr, hbuf, N_NODES,
                                                            sc1, sh1);
    node_dots<128><<<ND, 256, 0, stream>>>((const __half2*)hbuf, as2, ad2, e_n, f_n);
    attn_w<<<AW, 256, 0, stream>>>(srcs, ptr, e_n, f_n, wc);
    aggregate<128><<<N_NODES, 128, 0, stream>>>((const __half2*)hbuf, srcs, wc, ptr, b2,
                                                (float2*)out);
    hipMemsetAsync(csum, 0, 256 * 8, stream);
    hipMemsetAsync(csq,  0, 256 * 8, stream);
    bn_stats<256><<<400, 256, 0, stream>>>(out, csum, csq);
    bn_coef<256><<<1, 256, 0, stream>>>(csum, csq, g2, be2, sc2, sh2);

    // ---- Final linear 256 -> 256, in place, BN2+lrelu fused into staging ----
    gemm_mfma<256, 256, float><<<GB64, 256, 0, stream>>>(out, wtf, bf, out, N_NODES,
                                                         sc2, sh2);
}

// Round 5
// 514.621 us; speedup vs baseline: 2.5333x; 1.0847x over previous
//
#include <hip/hip_runtime.h>
#include <hip/hip_fp16.h>
#include <math.h>

#define N_NODES 50000
#define N_EDGES 800000
#define N_TOT   850000   // E + N self-loops
#define EPS_BN  1e-5f
#define GAT_SLOPE 0.2f
#define ACT_SLOPE 0.01f
#define SCAN_T   1024
#define N_TILES  ((N_NODES + SCAN_T - 1) / SCAN_T)   // 49

typedef _Float16 half8_t __attribute__((ext_vector_type(8)));
typedef _Float16 half4_t __attribute__((ext_vector_type(4)));
typedef float    f32x4   __attribute__((ext_vector_type(4)));

__device__ __forceinline__ float wred_max(float x) {
#pragma unroll
    for (int m = 32; m; m >>= 1) x = fmaxf(x, __shfl_xor(x, m, 64));
    return x;
}
__device__ __forceinline__ float wred_sum(float x) {
#pragma unroll
    for (int m = 32; m; m >>= 1) x += __shfl_xor(x, m, 64);
    return x;
}

__device__ __forceinline__ void store_val(float* p, float v) { *p = v; }
__device__ __forceinline__ void store_val(_Float16* p, float v) { *p = (_Float16)v; }

// ---- transpose + fp16-cast of W[K x C] -> Wt[C x K] ----
template<int K, int C>
__global__ void wcast_t(const float* __restrict__ W, _Float16* __restrict__ wt) {
    int i = blockIdx.x * 256 + threadIdx.x;
    if (i >= K * C) return;
    int k = i / C, c = i - k * C;          // coalesced read of W
    wt[(size_t)c * K + k] = (_Float16)W[i];
}

// ---- MFMA GEMM: out[n x C] = act(bn(x))[n x K] @ W[K x C] (+bias) ----
// 256 thr = 4 waves; 64 rows/block. Wave -> 64-col group (w % (C/64)), loops
// over RT=C/64 row-tiles; B-frags loaded once per k0 and reused across RT
// tiles (4*RT independent MFMAs per step). Optional fused BN+LeakyReLU on
// input during staging. If DOTS: epilogue computes e=h.a_s, f=h.a_d via
// 16-lane shfl reduce + LDS accumulation (replaces node_dots kernel).
// Layouts (verified m89/m120): A[m=lane&15][k=quad*8+j],
// B[k=quad*8+j][n=lane&15], C/D col=lane&15 row=quad*4+reg.
template<int K, int C, typename OutT, bool DOTS>
__global__ __launch_bounds__(256) void
gemm_mfma(const float* __restrict__ x, const _Float16* __restrict__ wt,
          const float* __restrict__ bias, OutT* __restrict__ out, int n,
          const float* __restrict__ scale, const float* __restrict__ shift,
          const float* __restrict__ a_s, const float* __restrict__ a_d,
          float* __restrict__ e_n, float* __restrict__ f_n) {
    constexpr int NW_C = C / 64;           // col groups per block (2 or 4)
    constexpr int RT   = NW_C;             // 16-row tiles per wave
    constexpr int LK   = K + 8;            // pad: keeps 16B alignment, spreads banks
    __shared__ _Float16 xs[64 * LK];
    __shared__ float ef_sh[2][64];
    const int row0 = blockIdx.x * 64;
    const int t = threadIdx.x;

    if (DOTS && t < 64) { ef_sh[0][t] = 0.f; ef_sh[1][t] = 0.f; }

    // stage 64 x K fp32 -> fp16 LDS (4 elems/thread/iter)
    for (int i = t * 4; i < 64 * K; i += 256 * 4) {
        int r = i / K, c = i - (i / K) * K;
        float4 v = make_float4(0.f, 0.f, 0.f, 0.f);
        if (row0 + r < n) v = *(const float4*)&x[(size_t)(row0 + r) * K + c];
        if (scale) {
            v.x = v.x * scale[c] + shift[c];         v.x = v.x > 0.f ? v.x : ACT_SLOPE * v.x;
            v.y = v.y * scale[c + 1] + shift[c + 1]; v.y = v.y > 0.f ? v.y : ACT_SLOPE * v.y;
            v.z = v.z * scale[c + 2] + shift[c + 2]; v.z = v.z > 0.f ? v.z : ACT_SLOPE * v.z;
            v.w = v.w * scale[c + 3] + shift[c + 3]; v.w = v.w > 0.f ? v.w : ACT_SLOPE * v.w;
        }
        half4_t h4 = { (_Float16)v.x, (_Float16)v.y, (_Float16)v.z, (_Float16)v.w };
        *(half4_t*)&xs[r * LK + c] = h4;
    }
    __syncthreads();

    const int w = t >> 6, l = t & 63;
    const int l16 = l & 15, quad = l >> 4;
    const int c0 = (w % NW_C) * 64;
    const int mbase = (w / NW_C) * (16 * NW_C);

    f32x4 acc[RT][4] = {};
    for (int k0 = 0; k0 < K; k0 += 32) {
        half8_t b[4];
#pragma unroll
        for (int tt = 0; tt < 4; ++tt)
            b[tt] = *(const half8_t*)&wt[(size_t)(c0 + tt * 16 + l16) * K + k0 + quad * 8];
        half8_t a[RT];
#pragma unroll
        for (int rt = 0; rt < RT; ++rt)
            a[rt] = *(const half8_t*)&xs[(mbase + rt * 16 + l16) * LK + k0 + quad * 8];
#pragma unroll
        for (int rt = 0; rt < RT; ++rt)
#pragma unroll
            for (int tt = 0; tt < 4; ++tt)
                acc[rt][tt] = __builtin_amdgcn_mfma_f32_16x16x32_f16(a[rt], b[tt],
                                                                     acc[rt][tt], 0, 0, 0);
    }

    // store + optional fused attention dots
#pragma unroll
    for (int rt = 0; rt < RT; ++rt) {
        int rb = row0 + mbase + rt * 16 + quad * 4;
#pragma unroll
        for (int tt = 0; tt < 4; ++tt) {
            int col = c0 + tt * 16 + l16;
            float bb = bias ? bias[col] : 0.f;
#pragma unroll
            for (int i = 0; i < 4; ++i)
                if (rb + i < n)
                    store_val(&out[(size_t)(rb + i) * C + col], acc[rt][tt][i] + bb);
        }
        if (DOTS) {
            float pe[4] = {0.f, 0.f, 0.f, 0.f}, pf[4] = {0.f, 0.f, 0.f, 0.f};
#pragma unroll
            for (int tt = 0; tt < 4; ++tt) {
                int col = c0 + tt * 16 + l16;
                float as_ = a_s[col], ad_ = a_d[col];
#pragma unroll
                for (int i = 0; i < 4; ++i) {
                    pe[i] += acc[rt][tt][i] * as_;
                    pf[i] += acc[rt][tt][i] * ad_;
                }
            }
#pragma unroll
            for (int m = 1; m < 16; m <<= 1)
#pragma unroll
                for (int i = 0; i < 4; ++i) {
                    pe[i] += __shfl_xor(pe[i], m, 64);
                    pf[i] += __shfl_xor(pf[i], m, 64);
                }
            if (l16 == 0) {
                int lr = mbase + rt * 16 + quad * 4;
#pragma unroll
                for (int i = 0; i < 4; ++i) {
                    atomicAdd(&ef_sh[0][lr + i], pe[i]);
                    atomicAdd(&ef_sh[1][lr + i], pf[i]);
                }
            }
        }
    }
    if (DOTS) {
        __syncthreads();
        if (t < 64 && row0 + t < n) {
            e_n[row0 + t] = ef_sh[0][t];
            f_n[row0 + t] = ef_sh[1][t];
        }
    }
}

// ---- CSR build over dst ----
__global__ void csr_count(const int* __restrict__ ei, int* __restrict__ cnt) {
    int e = blockIdx.x * blockDim.x + threadIdx.x;
    if (e >= N_TOT) return;
    int d = (e < N_EDGES) ? ei[N_EDGES + e] : (e - N_EDGES);
    atomicAdd(&cnt[d], 1);
}

__global__ void scan_phase1(const int* __restrict__ cnt, int* __restrict__ ptr,
                            int* __restrict__ tsum) {
    __shared__ int wsum[16];
    int base = blockIdx.x * SCAN_T;
    int t = threadIdx.x, lane = t & 63, w = t >> 6;
    int v = (base + t < N_NODES) ? cnt[base + t] : 0;
    int x = v;
#pragma unroll
    for (int off = 1; off < 64; off <<= 1) {
        int y = __shfl_up(x, off, 64);
        if (lane >= off) x += y;
    }
    if (lane == 63) wsum[w] = x;
    __syncthreads();
    if (t == 0) {
        int s = 0;
#pragma unroll
        for (int i = 0; i < 16; ++i) { int tmp = wsum[i]; wsum[i] = s; s += tmp; }
    }
    __syncthreads();
    int incl = x + wsum[w];
    if (base + t < N_NODES) ptr[base + t] = incl - v;
    if (t == SCAN_T - 1) tsum[blockIdx.x] = incl;
}

__global__ void scan_phase2(const int* __restrict__ tsum, int* __restrict__ toff,
                            int* __restrict__ ptr) {
    int t = threadIdx.x;
    int v = (t < N_TILES) ? tsum[t] : 0;
    int x = v;
#pragma unroll
    for (int off = 1; off < 64; off <<= 1) {
        int y = __shfl_up(x, off, 64);
        if (t >= off) x += y;
    }
    if (t < N_TILES) toff[t] = x - v;
    if (t == 63) ptr[N_NODES] = x;
}

__global__ void scan_phase3(int* __restrict__ ptr, const int* __restrict__ toff) {
    int i = blockIdx.x * SCAN_T + threadIdx.x;
    if (i < N_NODES) ptr[i] += toff[blockIdx.x];
}

__global__ void csr_fill_src(const int* __restrict__ ei, const int* __restrict__ ptr,
                             int* __restrict__ cur, int* __restrict__ srcs) {
    int e = blockIdx.x * blockDim.x + threadIdx.x;
    if (e >= N_TOT) return;
    int s, d;
    if (e < N_EDGES) { s = ei[e]; d = ei[N_EDGES + e]; }
    else { s = e - N_EDGES; d = s; }
    int pos = ptr[d] + atomicAdd(&cur[d], 1);
    srcs[pos] = s;
}

// ---- per-dst softmax weights, CSR order, pre-normalized. one wave per dst ----
__global__ void attn_w(const int* __restrict__ srcs, const int* __restrict__ ptr,
                       const float* __restrict__ e_n, const float* __restrict__ f_n,
                       float* __restrict__ wc) {
    int d = blockIdx.x * 4 + (threadIdx.x >> 6);
    int lane = threadIdx.x & 63;
    if (d >= N_NODES) return;
    int b0 = ptr[d], b1 = ptr[d + 1];
    float fd = f_n[d];
    float mymax = -1e30f;
    for (int j = b0 + lane; j < b1; j += 64) {
        float lg = e_n[srcs[j]] + fd;
        lg = lg > 0.f ? lg : GAT_SLOPE * lg;
        wc[j] = lg;
        mymax = fmaxf(mymax, lg);
    }
    float m = wred_max(mymax);
    float myden = 0.f;
    for (int j = b0 + lane; j < b1; j += 64) {
        float ex = __expf(wc[j] - m);
        wc[j] = ex;
        myden += ex;
    }
    float inv = 1.f / wred_sum(myden);
    for (int j = b0 + lane; j < b1; j += 64) wc[j] *= inv;
}

// ---- weighted gather aggregation: block per dst, blockDim == C/2, 4x unrolled ----
template<int C2>
__global__ void aggregate(const __half2* __restrict__ h, const int* __restrict__ srcs,
                          const float* __restrict__ wc, const int* __restrict__ ptr,
                          const float* __restrict__ bias, float2* __restrict__ out) {
    int d = blockIdx.x;
    int t = threadIdx.x;
    int b0 = ptr[d], b1 = ptr[d + 1];
    float ax = 0.f, ay = 0.f;
    int j = b0;
    for (; j + 4 <= b1; j += 4) {
        int s0 = srcs[j], s1 = srcs[j + 1], s2 = srcs[j + 2], s3 = srcs[j + 3];
        float w0 = wc[j], w1 = wc[j + 1], w2 = wc[j + 2], w3 = wc[j + 3];
        float2 v0 = __half22float2(h[(size_t)s0 * C2 + t]);
        float2 v1 = __half22float2(h[(size_t)s1 * C2 + t]);
        float2 v2 = __half22float2(h[(size_t)s2 * C2 + t]);
        float2 v3 = __half22float2(h[(size_t)s3 * C2 + t]);
        ax += w0 * v0.x + w1 * v1.x + w2 * v2.x + w3 * v3.x;
        ay += w0 * v0.y + w1 * v1.y + w2 * v2.y + w3 * v3.y;
    }
    for (; j < b1; ++j) {
        float w = wc[j];
        float2 v = __half22float2(h[(size_t)srcs[j] * C2 + t]);
        ax += w * v.x;
        ay += w * v.y;
    }
    out[(size_t)d * C2 + t] = make_float2(ax + bias[2 * t], ay + bias[2 * t + 1]);
}

// ---- BatchNorm stats + fused-coefficient computation ----
template<int C>
__global__ void bn_stats(const float* __restrict__ x, double* __restrict__ sum,
                         double* __restrict__ sumsq) {
    int t = threadIdx.x;
    double s = 0., q = 0.;
    for (int r = blockIdx.x; r < N_NODES; r += gridDim.x) {
        float v = x[(size_t)r * C + t];
        s += v;
        q += (double)v * v;
    }
    atomicAdd(&sum[t], s);
    atomicAdd(&sumsq[t], q);
}

template<int C>
__global__ void bn_coef(const double* __restrict__ sum, const double* __restrict__ sumsq,
                        const float* __restrict__ gamma, const float* __restrict__ beta,
                        float* __restrict__ scale, float* __restrict__ shift) {
    int c = threadIdx.x;
    float mu = (float)(sum[c] / N_NODES);
    float var = (float)(sumsq[c] / N_NODES) - mu * mu;
    float sc = gamma[c] * rsqrtf(var + EPS_BN);
    scale[c] = sc;
    shift[c] = beta[c] - mu * sc;
}

extern "C" void kernel_launch(void* const* d_in, const int* in_sizes, int n_in,
                              void* d_out, int out_size, void* d_ws, size_t ws_size,
                              hipStream_t stream) {
    const float* emb  = (const float*)d_in[0];
    const int*   ei   = (const int*)  d_in[1];
    const float* W1   = (const float*)d_in[2];
    const float* as1  = (const float*)d_in[3];
    const float* ad1  = (const float*)d_in[4];
    const float* b1   = (const float*)d_in[5];
    const float* g1   = (const float*)d_in[6];
    const float* be1  = (const float*)d_in[7];
    const float* W2   = (const float*)d_in[8];
    const float* as2  = (const float*)d_in[9];
    const float* ad2  = (const float*)d_in[10];
    const float* b2   = (const float*)d_in[11];
    const float* g2   = (const float*)d_in[12];
    const float* be2  = (const float*)d_in[13];
    const float* Wf   = (const float*)d_in[14];
    const float* bf   = (const float*)d_in[15];
    float* out = (float*)d_out;

    char* w = (char*)d_ws;
    auto alloc = [&](size_t bytes) {
        char* p = w;
        w += (bytes + 255) & ~(size_t)255;
        return (void*)p;
    };
    _Float16* hbuf = (_Float16*)alloc((size_t)N_NODES * 256 * 2); // h1/h2 fp16
    float*  x1   = (float*) alloc((size_t)N_NODES * 128 * 4);
    float*  e_n  = (float*) alloc((size_t)N_NODES * 4);
    float*  f_n  = (float*) alloc((size_t)N_NODES * 4);
    float*  wc   = (float*) alloc((size_t)N_TOT * 4);
    int*    srcs = (int*)   alloc((size_t)N_TOT * 4);
    int*    cnt  = (int*)   alloc((size_t)N_NODES * 4);
    int*    cur  = (int*)   alloc((size_t)N_NODES * 4);
    int*    ptr  = (int*)   alloc((size_t)(N_NODES + 1) * 4);
    int*    tsum = (int*)   alloc((size_t)N_TILES * 4);
    int*    toff = (int*)   alloc((size_t)N_TILES * 4);
    double* csum = (double*)alloc(256 * 8);
    double* csq  = (double*)alloc(256 * 8);
    float*  sc1  = (float*) alloc(128 * 4);
    float*  sh1  = (float*) alloc(128 * 4);
    float*  sc2  = (float*) alloc(256 * 4);
    float*  sh2  = (float*) alloc(256 * 4);
    _Float16* wt1 = (_Float16*)alloc((size_t)64 * 128 * 2);
    _Float16* wt2 = (_Float16*)alloc((size_t)128 * 256 * 2);
    _Float16* wtf = (_Float16*)alloc((size_t)256 * 256 * 2);

    const int EB   = (N_TOT + 255) / 256;
    const int GB64 = (N_NODES + 63) / 64;
    const int AW   = (N_NODES + 3) / 4;

    // ---- weight transpose+cast (small) ----
    wcast_t<64, 128><<<(64 * 128 + 255) / 256, 256, 0, stream>>>(W1, wt1);
    wcast_t<128, 256><<<(128 * 256 + 255) / 256, 256, 0, stream>>>(W2, wt2);
    wcast_t<256, 256><<<(256 * 256 + 255) / 256, 256, 0, stream>>>(Wf, wtf);

    // ---- CSR build (shared by both layers) ----
    hipMemsetAsync(cnt, 0, (size_t)N_NODES * 4, stream);
    hipMemsetAsync(cur, 0, (size_t)N_NODES * 4, stream);
    csr_count<<<EB, 256, 0, stream>>>(ei, cnt);
    scan_phase1<<<N_TILES, SCAN_T, 0, stream>>>(cnt, ptr, tsum);
    scan_phase2<<<1, 64, 0, stream>>>(tsum, toff, ptr);
    scan_phase3<<<N_TILES, SCAN_T, 0, stream>>>(ptr, toff);
    csr_fill_src<<<EB, 256, 0, stream>>>(ei, ptr, cur, srcs);

    // ---- Layer 1: 64 -> 128 (dots fused) ----
    gemm_mfma<64, 128, _Float16, true><<<GB64, 256, 0, stream>>>(
        emb, wt1, nullptr, hbuf, N_NODES, nullptr, nullptr, as1, ad1, e_n, f_n);
    attn_w<<<AW, 256, 0, stream>>>(srcs, ptr, e_n, f_n, wc);
    aggregate<64><<<N_NODES, 64, 0, stream>>>((const __half2*)hbuf, srcs, wc, ptr, b1,
                                              (float2*)x1);
    hipMemsetAsync(csum, 0, 256 * 8, stream);
    hipMemsetAsync(csq,  0, 256 * 8, stream);
    bn_stats<128><<<400, 128, 0, stream>>>(x1, csum, csq);
    bn_coef<128><<<1, 128, 0, stream>>>(csum, csq, g1, be1, sc1, sh1);

    // ---- Layer 2: 128 -> 256 (BN1+lrelu fused into staging, dots fused) ----
    gemm_mfma<128, 256, _Float16, true><<<GB64, 256, 0, stream>>>(
        x1, wt2, nullptr, hbuf, N_NODES, sc1, sh1, as2, ad2, e_n, f_n);
    attn_w<<<AW, 256, 0, stream>>>(srcs, ptr, e_n, f_n, wc);
    aggregate<128><<<N_NODES, 128, 0, stream>>>((const __half2*)hbuf, srcs, wc, ptr, b2,
                                                (float2*)out);
    hipMemsetAsync(csum, 0, 256 * 8, stream);
    hipMemsetAsync(csq,  0, 256 * 8, stream);
    bn_stats<256><<<400, 256, 0, stream>>>(out, csum, csq);
    bn_coef<256><<<1, 256, 0, stream>>>(csum, csq, g2, be2, sc2, sh2);

    // ---- Final linear 256 -> 256, in place, BN2+lrelu fused into staging ----
    gemm_mfma<256, 256, float, false><<<GB64, 256, 0, stream>>>(
        out, wtf, bf, out, N_NODES, sc2, sh2, nullptr, nullptr, nullptr, nullptr);
}